// Round 16
// baseline (40.053 us; speedup 1.0000x reference)
//
#include <hip/hip_runtime.h>

constexpr int N_CTRL  = 25;
constexpr int IMG_H   = 256;
constexpr int IMG_W   = 192;
constexpr int BATCH   = 64;
constexpr int BCHUNK  = 2;                    // batches per thread
constexpr int PLANE   = IMG_H * IMG_W;
constexpr int PIX_BLOCKS = PLANE / 512;       // 96 (512 px per block, 2 per thread)
constexpr int NWG = PIX_BLOCKS * (BATCH / BCHUNK);  // 3072, divisible by 8
constexpr float RBF_SCALE = 10.0f;
constexpr float OFF_SCALE = 0.3f;

typedef float vf2 __attribute__((ext_vector_type(2)));

__device__ __forceinline__ float bilin(float wx, float wy, vf2 r0, vf2 r1) {
    const float top = fmaf(wx, r0[1] - r0[0], r0[0]);
    const float bot = fmaf(wx, r1[1] - r1[0], r1[0]);
    return fmaf(wy, bot - top, top);
}

// 6 volatile gather loads for one (pixel,batch) unit; row-pair via offset:768.
#define LOAD6(PBASE, VA0, VA1, VB0, VB1, VC0, VC1) do {                        \
    const float* p0_ = (PBASE);                                                \
    const float* p1_ = p0_ + PLANE;                                            \
    const float* p2_ = p1_ + PLANE;                                            \
    asm volatile("global_load_dwordx2 %0, %1, off"            : "=v"(VA0) : "v"(p0_)); \
    asm volatile("global_load_dwordx2 %0, %1, off offset:768" : "=v"(VA1) : "v"(p0_)); \
    asm volatile("global_load_dwordx2 %0, %1, off"            : "=v"(VB0) : "v"(p1_)); \
    asm volatile("global_load_dwordx2 %0, %1, off offset:768" : "=v"(VB1) : "v"(p1_)); \
    asm volatile("global_load_dwordx2 %0, %1, off"            : "=v"(VC0) : "v"(p2_)); \
    asm volatile("global_load_dwordx2 %0, %1, off offset:768" : "=v"(VC1) : "v"(p2_)); \
} while (0)

// Counted wait that PINS one unit's values (inputs AND outputs).
#define WAIT6(N, V0, V1, V2, V3, V4, V5)                                       \
    asm volatile("s_waitcnt vmcnt(" #N ")"                                     \
                 : "+v"(V0), "+v"(V1), "+v"(V2), "+v"(V3), "+v"(V4), "+v"(V5))

__global__ __launch_bounds__(256, 4) void tps_warp_kernel(
    const float* __restrict__ cloth,   // (64,3,256,192)
    const float* __restrict__ theta,   // (64,50)
    float* __restrict__ out)           // (64,3,256,192)
{
    // XCD swizzle, 4 sequential phases per XCD (phase footprint ~1.2 MB < L2).
    const int flat = blockIdx.x;
    const int xcd  = flat & 7;
    const int w    = flat >> 3;              // [0, 384)
    const int pb   = w % PIX_BLOCKS;
    const int ph   = w / PIX_BLOCKS;         // phase 0..3
    const int b0   = (xcd * 4 + ph) * BCHUNK;

    // Thread owns horizontally-adjacent pixels 2t, 2t+1 (same row: W even).
    const int pix0 = pb * 512 + 2 * threadIdx.x;
    const int hh  = pix0 / IMG_W;
    const int wwa = pix0 - hh * IMG_W;       // even
    const float mxa = -1.0f + (2.0f / (IMG_W - 1)) * (float)wwa;
    const float mxb = mxa + (2.0f / (IMG_W - 1));
    const float my  = -1.0f + (2.0f / (IMG_H - 1)) * (float)hh;

    // Separable RBF: ey shared by the pixel pair -> 15 exps for 4 units.
#define RB(d) __expf(-(d) * (d) * RBF_SCALE)
    const float exa0 = RB(mxa + 0.90f), exa1 = RB(mxa + 0.45f), exa2 = RB(mxa),
                exa3 = RB(mxa - 0.45f), exa4 = RB(mxa - 0.90f);
    const float exb0 = RB(mxb + 0.90f), exb1 = RB(mxb + 0.45f), exb2 = RB(mxb),
                exb3 = RB(mxb - 0.45f), exb4 = RB(mxb - 0.90f);
    const float ey0 = RB(my + 0.90f), ey1 = RB(my + 0.45f), ey2 = RB(my),
                ey3 = RB(my - 0.45f), ey4 = RB(my - 0.90f);
#undef RB

    // ---- phase A: 2 pixels x 2 batches offset accumulation, named scalars.
    const float* t0 = theta + (size_t)(b0 + 0) * (2 * N_CTRL);
    const float* t1 = theta + (size_t)(b0 + 1) * (2 * N_CTRL);
    float oxa0 = 0, oya0 = 0, oxb0 = 0, oyb0 = 0;   // pixels a,b of batch 0
    float oxa1 = 0, oya1 = 0, oxb1 = 0, oyb1 = 0;   // pixels a,b of batch 1
#define TERM(n, EXA, EXB, EY) {                                                \
    const float wa_ = OFF_SCALE * (EXA) * (EY);                                \
    const float wb_ = OFF_SCALE * (EXB) * (EY);                                \
    oxa0 = fmaf(t0[2*(n)], wa_, oxa0); oya0 = fmaf(t0[2*(n)+1], wa_, oya0);    \
    oxb0 = fmaf(t0[2*(n)], wb_, oxb0); oyb0 = fmaf(t0[2*(n)+1], wb_, oyb0);    \
    oxa1 = fmaf(t1[2*(n)], wa_, oxa1); oya1 = fmaf(t1[2*(n)+1], wa_, oya1);    \
    oxb1 = fmaf(t1[2*(n)], wb_, oxb1); oyb1 = fmaf(t1[2*(n)+1], wb_, oyb1); }
    TERM( 0, exa0, exb0, ey0) TERM( 1, exa1, exb1, ey0) TERM( 2, exa2, exb2, ey0) TERM( 3, exa3, exb3, ey0) TERM( 4, exa4, exb4, ey0)
    TERM( 5, exa0, exb0, ey1) TERM( 6, exa1, exb1, ey1) TERM( 7, exa2, exb2, ey1) TERM( 8, exa3, exb3, ey1) TERM( 9, exa4, exb4, ey1)
    TERM(10, exa0, exb0, ey2) TERM(11, exa1, exb1, ey2) TERM(12, exa2, exb2, ey2) TERM(13, exa3, exb3, ey2) TERM(14, exa4, exb4, ey2)
    TERM(15, exa0, exb0, ey3) TERM(16, exa1, exb1, ey3) TERM(17, exa2, exb2, ey3) TERM(18, exa3, exb3, ey3) TERM(19, exa4, exb4, ey3)
    TERM(20, exa0, exb0, ey4) TERM(21, exa1, exb1, ey4) TERM(22, exa2, exb2, ey4) TERM(23, exa3, exb3, ey4) TERM(24, exa4, exb4, ey4)
#undef TERM

#define COORD(MX, OX, OY, SX, SY)                                              \
    const float SX = (fminf(fmaxf((MX) + (OX), -1.0f), 1.0f) + 1.0f) * (0.5f * (float)(IMG_W - 1)); \
    const float SY = (fminf(fmaxf(my + (OY), -1.0f), 1.0f) + 1.0f) * (0.5f * (float)(IMG_H - 1));
    COORD(mxa, oxa0, oya0, sxa0, sya0)
    COORD(mxb, oxb0, oyb0, sxb0, syb0)
    COORD(mxa, oxa1, oya1, sxa1, sya1)
    COORD(mxb, oxb1, oyb1, sxb1, syb1)
#undef COORD

    const size_t img_stride = (size_t)3 * PLANE;
    const float* imgb = cloth + (size_t)b0 * img_stride;

#define PBASE(B, SX, SY) (imgb + (size_t)(B) * img_stride +                    \
    (size_t)(min((int)(SY), IMG_H - 2) * IMG_W + min((int)(SX), IMG_W - 2)))

    // ---- phase B: 4 units, ALL 24 loads issued before the first wait;
    // descending counted pins (18/12/6/0) -> one deep latency exposure.
    vf2 pA0, pA1, pB0, pB1, pC0, pC1;  // (px a, batch 0)
    vf2 qA0, qA1, qB0, qB1, qC0, qC1;  // (px b, batch 0)
    vf2 rA0, rA1, rB0, rB1, rC0, rC1;  // (px a, batch 1)
    vf2 sA0, sA1, sB0, sB1, sC0, sC1;  // (px b, batch 1)
    float rp0, rp1, rp2, rq0, rq1, rq2, rr0, rr1, rr2, rs0, rs1, rs2;

#define BLEND(SX, SY, V0, V1, V2, V3, V4, V5, R0, R1, R2) {                    \
    const float wx_ = (SX) - (float)min((int)(SX), IMG_W - 2);                 \
    const float wy_ = (SY) - (float)min((int)(SY), IMG_H - 2);                 \
    R0 = bilin(wx_, wy_, V0, V1);                                              \
    R1 = bilin(wx_, wy_, V2, V3);                                              \
    R2 = bilin(wx_, wy_, V4, V5); }

    LOAD6(PBASE(0, sxa0, sya0), pA0, pA1, pB0, pB1, pC0, pC1);
    LOAD6(PBASE(0, sxb0, syb0), qA0, qA1, qB0, qB1, qC0, qC1);
    LOAD6(PBASE(1, sxa1, sya1), rA0, rA1, rB0, rB1, rC0, rC1);
    LOAD6(PBASE(1, sxb1, syb1), sA0, sA1, sB0, sB1, sC0, sC1);
    WAIT6(18, pA0, pA1, pB0, pB1, pC0, pC1);
    BLEND(sxa0, sya0, pA0, pA1, pB0, pB1, pC0, pC1, rp0, rp1, rp2);
    WAIT6(12, qA0, qA1, qB0, qB1, qC0, qC1);
    BLEND(sxb0, syb0, qA0, qA1, qB0, qB1, qC0, qC1, rq0, rq1, rq2);
    WAIT6(6, rA0, rA1, rB0, rB1, rC0, rC1);
    BLEND(sxa1, sya1, rA0, rA1, rB0, rB1, rC0, rC1, rr0, rr1, rr2);
    WAIT6(0, sA0, sA1, sB0, sB1, sC0, sC1);
    BLEND(sxb1, syb1, sA0, sA1, sB0, sB1, sC0, sC1, rs0, rs1, rs2);
#undef BLEND
#undef PBASE

    // ---- phase C: MERGED float2 NT stores (adjacent pixels): 6 VMEM for
    // 4 units (was 12). The only proven lever (R4->R5) is VMEM-instr count.
    float* o0 = out + (size_t)(b0 + 0) * img_stride + hh * IMG_W + wwa;
    float* o1 = out + (size_t)(b0 + 1) * img_stride + hh * IMG_W + wwa;
    __builtin_nontemporal_store(vf2{rp0, rq0}, (vf2*)(o0));
    __builtin_nontemporal_store(vf2{rp1, rq1}, (vf2*)(o0 + PLANE));
    __builtin_nontemporal_store(vf2{rp2, rq2}, (vf2*)(o0 + 2 * PLANE));
    __builtin_nontemporal_store(vf2{rr0, rs0}, (vf2*)(o1));
    __builtin_nontemporal_store(vf2{rr1, rs1}, (vf2*)(o1 + PLANE));
    __builtin_nontemporal_store(vf2{rr2, rs2}, (vf2*)(o1 + 2 * PLANE));
}

extern "C" void kernel_launch(void* const* d_in, const int* in_sizes, int n_in,
                              void* d_out, int out_size, void* d_ws, size_t ws_size,
                              hipStream_t stream) {
    const float* cloth = (const float*)d_in[0];
    const float* theta = (const float*)d_in[1];
    float* out = (float*)d_out;

    tps_warp_kernel<<<dim3(NWG), dim3(256), 0, stream>>>(cloth, theta, out);
}

// Round 17
// 38.241 us; speedup vs baseline: 1.0474x; 1.0474x over previous
//
#include <hip/hip_runtime.h>

constexpr int N_CTRL  = 25;
constexpr int IMG_H   = 256;
constexpr int IMG_W   = 192;
constexpr int PLANE   = IMG_H * IMG_W;
constexpr int PIX_BLOCKS = PLANE / 256;   // 192
constexpr int NWG = PIX_BLOCKS * 8;       // 1536 persistent blocks = exactly 6/CU
constexpr float RBF_SCALE = 10.0f;
constexpr float OFF_SCALE = 0.3f;

typedef float vf2 __attribute__((ext_vector_type(2)));

__device__ __forceinline__ float bilin(float wx, float wy, vf2 r0, vf2 r1) {
    const float top = fmaf(wx, r0[1] - r0[0], r0[0]);
    const float bot = fmaf(wx, r1[1] - r1[0], r1[0]);
    return fmaf(wy, bot - top, top);
}

// 6 volatile gather loads for one batch: 3 channel-pointers, row-pair via
// offset:768 (= IMG_W floats). Volatile asm: cannot be deleted/reordered/sunk.
#define LOAD6(PBASE, VA0, VA1, VB0, VB1, VC0, VC1) do {                        \
    const float* p0_ = (PBASE);                                                \
    const float* p1_ = p0_ + PLANE;                                            \
    const float* p2_ = p1_ + PLANE;                                            \
    asm volatile("global_load_dwordx2 %0, %1, off"            : "=v"(VA0) : "v"(p0_)); \
    asm volatile("global_load_dwordx2 %0, %1, off offset:768" : "=v"(VA1) : "v"(p0_)); \
    asm volatile("global_load_dwordx2 %0, %1, off"            : "=v"(VB0) : "v"(p1_)); \
    asm volatile("global_load_dwordx2 %0, %1, off offset:768" : "=v"(VB1) : "v"(p1_)); \
    asm volatile("global_load_dwordx2 %0, %1, off"            : "=v"(VC0) : "v"(p2_)); \
    asm volatile("global_load_dwordx2 %0, %1, off offset:768" : "=v"(VC1) : "v"(p2_)); \
} while (0)

// Counted wait that PINS one batch's values (inputs AND outputs): its loads
// must precede, its blends must follow. Never drain to 0 until batch-B.
#define WAIT6(N, V0, V1, V2, V3, V4, V5)                                       \
    asm volatile("s_waitcnt vmcnt(" #N ")"                                     \
                 : "+v"(V0), "+v"(V1), "+v"(V2), "+v"(V3), "+v"(V4), "+v"(V5))

__global__ __launch_bounds__(256, 4) void tps_warp_kernel(
    const float* __restrict__ cloth,   // (64,3,256,192)
    const float* __restrict__ theta,   // (64,50)
    float* __restrict__ out)           // (64,3,256,192)
{
    // PERSISTENT blocks: 1536 = 192 pixel-blocks x 8 XCDs, exactly 6/CU,
    // resident for the whole kernel (sustained ~24 waves/CU). Each block
    // grid-strides over its XCD's 4 batch-phases; per-phase XCD footprint
    // stays ~1.2 MB < 4 MiB private L2 (R13 structure, now time-amortized).
    const int xcd = blockIdx.x & 7;
    const int pb  = blockIdx.x >> 3;

    const int pix = pb * 256 + threadIdx.x;
    const int hh = pix / IMG_W;
    const int ww = pix - hh * IMG_W;
    const float mx = -1.0f + (2.0f / (IMG_W - 1)) * (float)ww;
    const float my = -1.0f + (2.0f / (IMG_H - 1)) * (float)hh;

    // Separable RBF basis — hoisted: computed ONCE per block (R13 paid this
    // 4x, once per phase-block). All named scalars (aggregates -> scratch).
#define RB(d) __expf(-(d) * (d) * RBF_SCALE)
    const float ex0 = RB(mx + 0.90f), ex1 = RB(mx + 0.45f), ex2 = RB(mx),
                ex3 = RB(mx - 0.45f), ex4 = RB(mx - 0.90f);
    const float ey0 = RB(my + 0.90f), ey1 = RB(my + 0.45f), ey2 = RB(my),
                ey3 = RB(my - 0.45f), ey4 = RB(my - 0.90f);
#undef RB

    const size_t img_stride = (size_t)3 * PLANE;

    for (int ph = 0; ph < 4; ++ph) {
        const int b0 = xcd * 8 + ph * 2;   // 2 batches per iteration

        // ---- phase A: 2 batches' offset accumulation (theta via SGPR
        // s_loads; named accumulators).
        const float* t0 = theta + (size_t)(b0 + 0) * (2 * N_CTRL);
        const float* t1 = theta + (size_t)(b0 + 1) * (2 * N_CTRL);
        float ox0 = 0, oy0 = 0, ox1 = 0, oy1 = 0;
#define TERM(n, EX, EY) {                                                      \
        const float w_ = OFF_SCALE * (EX) * (EY);                              \
        ox0 = fmaf(t0[2*(n)], w_, ox0); oy0 = fmaf(t0[2*(n)+1], w_, oy0);      \
        ox1 = fmaf(t1[2*(n)], w_, ox1); oy1 = fmaf(t1[2*(n)+1], w_, oy1); }
        TERM( 0, ex0, ey0) TERM( 1, ex1, ey0) TERM( 2, ex2, ey0) TERM( 3, ex3, ey0) TERM( 4, ex4, ey0)
        TERM( 5, ex0, ey1) TERM( 6, ex1, ey1) TERM( 7, ex2, ey1) TERM( 8, ex3, ey1) TERM( 9, ex4, ey1)
        TERM(10, ex0, ey2) TERM(11, ex1, ey2) TERM(12, ex2, ey2) TERM(13, ex3, ey2) TERM(14, ex4, ey2)
        TERM(15, ex0, ey3) TERM(16, ex1, ey3) TERM(17, ex2, ey3) TERM(18, ex3, ey3) TERM(19, ex4, ey3)
        TERM(20, ex0, ey4) TERM(21, ex1, ey4) TERM(22, ex2, ey4) TERM(23, ex3, ey4) TERM(24, ex4, ey4)
#undef TERM

        const float sx0 = (fminf(fmaxf(mx + ox0, -1.0f), 1.0f) + 1.0f) * (0.5f * (float)(IMG_W - 1));
        const float sy0 = (fminf(fmaxf(my + oy0, -1.0f), 1.0f) + 1.0f) * (0.5f * (float)(IMG_H - 1));
        const float sx1 = (fminf(fmaxf(mx + ox1, -1.0f), 1.0f) + 1.0f) * (0.5f * (float)(IMG_W - 1));
        const float sy1 = (fminf(fmaxf(my + oy1, -1.0f), 1.0f) + 1.0f) * (0.5f * (float)(IMG_H - 1));

        const float* imgb = cloth + (size_t)b0 * img_stride;
        float*       outb = out   + (size_t)b0 * img_stride + pix;

#define PBASE(B, SX, SY) (imgb + (size_t)(B) * img_stride +                    \
        (size_t)(min((int)(SY), IMG_H - 2) * IMG_W + min((int)(SX), IMG_W - 2)))

        // ---- phase B: depth-12 pipeline (both batches fully in flight),
        // counted waits pin each batch's consumes (R13 structure).
        vf2 a0, a1, a2, a3, a4, a5;        // batch 0
        vf2 b0v, b1v, b2v, b3v, b4v, b5v;  // batch 1
        float r00, r01, r02, r10, r11, r12;

#define BLEND(SX, SY, V0, V1, V2, V3, V4, V5, R0, R1, R2) {                    \
        const float wx_ = (SX) - (float)min((int)(SX), IMG_W - 2);             \
        const float wy_ = (SY) - (float)min((int)(SY), IMG_H - 2);             \
        R0 = bilin(wx_, wy_, V0, V1);                                          \
        R1 = bilin(wx_, wy_, V2, V3);                                          \
        R2 = bilin(wx_, wy_, V4, V5); }

        LOAD6(PBASE(0, sx0, sy0), a0, a1, a2, a3, a4, a5);
        LOAD6(PBASE(1, sx1, sy1), b0v, b1v, b2v, b3v, b4v, b5v);
        // vmcnt(6): also drains the previous iteration's 6 (older) stores —
        // regular stores ack at L2, so that drain is cheap and already
        // overlapped with this iteration's phase-A VALU work.
        WAIT6(6, a0, a1, a2, a3, a4, a5);
        BLEND(sx0, sy0, a0, a1, a2, a3, a4, a5, r00, r01, r02);
        WAIT6(0, b0v, b1v, b2v, b3v, b4v, b5v);
        BLEND(sx1, sy1, b0v, b1v, b2v, b3v, b4v, b5v, r10, r11, r12);
#undef BLEND
#undef PBASE

        // ---- phase C: regular stores (L2-ack; avoids coupling next
        // iteration's counted wait to an HBM write drain).
        float* o0 = outb;
        float* o1 = outb + img_stride;
        o0[0]         = r00;
        o0[PLANE]     = r01;
        o0[2 * PLANE] = r02;
        o1[0]         = r10;
        o1[PLANE]     = r11;
        o1[2 * PLANE] = r12;
    }
}

extern "C" void kernel_launch(void* const* d_in, const int* in_sizes, int n_in,
                              void* d_out, int out_size, void* d_ws, size_t ws_size,
                              hipStream_t stream) {
    const float* cloth = (const float*)d_in[0];
    const float* theta = (const float*)d_in[1];
    float* out = (float*)d_out;

    tps_warp_kernel<<<dim3(NWG), dim3(256), 0, stream>>>(cloth, theta, out);
}

// Round 18
// 35.246 us; speedup vs baseline: 1.1364x; 1.0850x over previous
//
#include <hip/hip_runtime.h>

constexpr int GRID_SZ = 5;
constexpr int N_CTRL  = 25;
constexpr int IMG_H   = 256;
constexpr int IMG_W   = 192;
constexpr int BATCH   = 64;
constexpr int BCHUNK  = 2;    // batches per thread; 4 sequential phases per XCD
constexpr int PLANE   = IMG_H * IMG_W;
constexpr int PIX_BLOCKS = PLANE / 256;             // 192
constexpr int NWG = PIX_BLOCKS * (BATCH / BCHUNK);  // 6144
constexpr float RBF_SCALE = 10.0f;
constexpr float OFF_SCALE = 0.3f;

typedef float vf2 __attribute__((ext_vector_type(2)));

__device__ __forceinline__ float bilin(float wx, float wy, vf2 r0, vf2 r1) {
    const float top = fmaf(wx, r0[1] - r0[0], r0[0]);
    const float bot = fmaf(wx, r1[1] - r1[0], r1[0]);
    return fmaf(wy, bot - top, top);
}

// 6 volatile gather loads for one batch: 3 channel-pointers, row-pair via
// offset:768 (= IMG_W floats). Volatile asm: cannot be deleted/reordered/sunk.
#define LOAD6(PBASE, VA0, VA1, VB0, VB1, VC0, VC1) do {                        \
    const float* p0_ = (PBASE);                                                \
    const float* p1_ = p0_ + PLANE;                                            \
    const float* p2_ = p1_ + PLANE;                                            \
    asm volatile("global_load_dwordx2 %0, %1, off"            : "=v"(VA0) : "v"(p0_)); \
    asm volatile("global_load_dwordx2 %0, %1, off offset:768" : "=v"(VA1) : "v"(p0_)); \
    asm volatile("global_load_dwordx2 %0, %1, off"            : "=v"(VB0) : "v"(p1_)); \
    asm volatile("global_load_dwordx2 %0, %1, off offset:768" : "=v"(VB1) : "v"(p1_)); \
    asm volatile("global_load_dwordx2 %0, %1, off"            : "=v"(VC0) : "v"(p2_)); \
    asm volatile("global_load_dwordx2 %0, %1, off offset:768" : "=v"(VC1) : "v"(p2_)); \
} while (0)

// Counted wait that PINS one batch's values (inputs AND outputs): its loads
// must precede, its blends must follow. T4: never drain to 0 until the end.
#define WAIT6(N, V0, V1, V2, V3, V4, V5)                                       \
    asm volatile("s_waitcnt vmcnt(" #N ")"                                     \
                 : "+v"(V0), "+v"(V1), "+v"(V2), "+v"(V3), "+v"(V4), "+v"(V5))

__global__ __launch_bounds__(256, 4) void tps_warp_kernel(
    const float* __restrict__ cloth,   // (64,3,256,192)
    const float* __restrict__ theta,   // (64,50)
    float* __restrict__ out)           // (64,3,256,192)
{
    // XCD swizzle with 4 sequential phases per XCD (phase footprint ~1.2 MB
    // < 4 MiB private L2). Best measured structure (R13: 35.18 us).
    const int flat = blockIdx.x;
    const int xcd  = flat & 7;
    const int w    = flat >> 3;          // [0, 768) per XCD, dispatched in order
    const int pb   = w % PIX_BLOCKS;
    const int ph   = w / PIX_BLOCKS;     // phase 0..3, temporally sequential
    const int b0   = (xcd * 4 + ph) * BCHUNK;

    const int pix = pb * 256 + threadIdx.x;
    const int hh = pix / IMG_W;
    const int ww = pix - hh * IMG_W;
    const float mx = -1.0f + (2.0f / (IMG_W - 1)) * (float)ww;
    const float my = -1.0f + (2.0f / (IMG_H - 1)) * (float)hh;

    // Separable RBF basis — all named scalars (aggregates risk demotion).
#define RB(d) __expf(-(d) * (d) * RBF_SCALE)
    const float ex0 = RB(mx + 0.90f), ex1 = RB(mx + 0.45f), ex2 = RB(mx),
                ex3 = RB(mx - 0.45f), ex4 = RB(mx - 0.90f);
    const float ey0 = RB(my + 0.90f), ey1 = RB(my + 0.45f), ey2 = RB(my),
                ey3 = RB(my - 0.45f), ey4 = RB(my - 0.90f);
#undef RB

    // ---- phase A: 2 batches' offset accumulation, named accumulators.
    const float* t0 = theta + (size_t)(b0 + 0) * (2 * N_CTRL);
    const float* t1 = theta + (size_t)(b0 + 1) * (2 * N_CTRL);
    float ox0 = 0, oy0 = 0, ox1 = 0, oy1 = 0;
#define TERM(n, EX, EY) {                                                      \
    const float w_ = OFF_SCALE * (EX) * (EY);                                  \
    ox0 = fmaf(t0[2*(n)], w_, ox0); oy0 = fmaf(t0[2*(n)+1], w_, oy0);          \
    ox1 = fmaf(t1[2*(n)], w_, ox1); oy1 = fmaf(t1[2*(n)+1], w_, oy1); }
    TERM( 0, ex0, ey0) TERM( 1, ex1, ey0) TERM( 2, ex2, ey0) TERM( 3, ex3, ey0) TERM( 4, ex4, ey0)
    TERM( 5, ex0, ey1) TERM( 6, ex1, ey1) TERM( 7, ex2, ey1) TERM( 8, ex3, ey1) TERM( 9, ex4, ey1)
    TERM(10, ex0, ey2) TERM(11, ex1, ey2) TERM(12, ex2, ey2) TERM(13, ex3, ey2) TERM(14, ex4, ey2)
    TERM(15, ex0, ey3) TERM(16, ex1, ey3) TERM(17, ex2, ey3) TERM(18, ex3, ey3) TERM(19, ex4, ey3)
    TERM(20, ex0, ey4) TERM(21, ex1, ey4) TERM(22, ex2, ey4) TERM(23, ex3, ey4) TERM(24, ex4, ey4)
#undef TERM

#define COORD(OX, OY, SX, SY)                                                  \
    const float SX = (fminf(fmaxf(mx + (OX), -1.0f), 1.0f) + 1.0f) * (0.5f * (float)(IMG_W - 1)); \
    const float SY = (fminf(fmaxf(my + (OY), -1.0f), 1.0f) + 1.0f) * (0.5f * (float)(IMG_H - 1));
    COORD(ox0, oy0, sx0, sy0)
    COORD(ox1, oy1, sx1, sy1)
#undef COORD

    const size_t img_stride = (size_t)3 * PLANE;
    const float* imgb = cloth + (size_t)b0 * img_stride;
    float*       outb = out   + (size_t)b0 * img_stride + pix;

#define PBASE(B, SX, SY) (imgb + (size_t)(B) * img_stride +                    \
    (size_t)(min((int)(SY), IMG_H - 2) * IMG_W + min((int)(SX), IMG_W - 2)))

    // ---- phase B: depth-12 pipeline (both batches fully in flight; only
    // 24 VGPRs of load data), counted waits pin each batch's consumes.
    vf2 a0, a1, a2, a3, a4, a5;        // batch 0
    vf2 b0v, b1v, b2v, b3v, b4v, b5v;  // batch 1
    float r00, r01, r02, r10, r11, r12;

#define BLEND(SX, SY, V0, V1, V2, V3, V4, V5, R0, R1, R2) {                    \
    const float wx_ = (SX) - (float)min((int)(SX), IMG_W - 2);                 \
    const float wy_ = (SY) - (float)min((int)(SY), IMG_H - 2);                 \
    R0 = bilin(wx_, wy_, V0, V1);                                              \
    R1 = bilin(wx_, wy_, V2, V3);                                              \
    R2 = bilin(wx_, wy_, V4, V5); }

    LOAD6(PBASE(0, sx0, sy0), a0, a1, a2, a3, a4, a5);
    LOAD6(PBASE(1, sx1, sy1), b0v, b1v, b2v, b3v, b4v, b5v);
    WAIT6(6, a0, a1, a2, a3, a4, a5);
    BLEND(sx0, sy0, a0, a1, a2, a3, a4, a5, r00, r01, r02);
    WAIT6(0, b0v, b1v, b2v, b3v, b4v, b5v);
    BLEND(sx1, sy1, b0v, b1v, b2v, b3v, b4v, b5v, r10, r11, r12);
#undef BLEND
#undef PBASE

    // ---- phase C: 6 NT stores at the end (nothing waits on them).
    float* o0 = outb;
    float* o1 = outb + img_stride;
    __builtin_nontemporal_store(r00, o0);
    __builtin_nontemporal_store(r01, o0 + PLANE);
    __builtin_nontemporal_store(r02, o0 + 2 * PLANE);
    __builtin_nontemporal_store(r10, o1);
    __builtin_nontemporal_store(r11, o1 + PLANE);
    __builtin_nontemporal_store(r12, o1 + 2 * PLANE);
}

extern "C" void kernel_launch(void* const* d_in, const int* in_sizes, int n_in,
                              void* d_out, int out_size, void* d_ws, size_t ws_size,
                              hipStream_t stream) {
    const float* cloth = (const float*)d_in[0];
    const float* theta = (const float*)d_in[1];
    float* out = (float*)d_out;

    tps_warp_kernel<<<dim3(NWG), dim3(256), 0, stream>>>(cloth, theta, out);
}